// Round 16
// baseline (66.397 us; speedup 1.0000x reference)
//
#include <hip/hip_runtime.h>
#include <hip/hip_bf16.h>

// MixMIL — R16: barrier-free fused MFMA proj + per-bag softmax pooling.
// Shapes: I=512000, Q=128, P=1, S=8, N=4000. x f32, betas f32, seg int32 sorted.
//
// Algebra: accumulate with raw beta_z; b = rms(beta_z) applied only at the end.
// Max-free softmax (|u|max ~62 << 88, f32-exp safe; R15-verified).
// 3-MFMA hi/lo bf16 split for f32-grade accuracy (R14-verified, absmax 1.56e-2).
//
// R16 structure (R15's 3 barriers/tile exposed staging latency):
//  - one bag per WAVE, fully independent: per-wave 16-row tiles,
//    per-wave double-buffered LDS (2 x 8KB), ZERO __syncthreads.
//  - staging via global_load_lds width=16: linear LDS dest, PRE-SWIZZLED
//    per-lane source cols (c4 ^ (r&7)) so MFMA b128 reads are ~2-way (free).
//  - counted s_waitcnt vmcnt(8): issue tile j+1's 8 loads, wait until only
//    they remain -> tile j ready; vmcnt(0) only on the last tile.
//  - pool entirely in-register: C-layout row=(lane>>4)*4+i, col=lane&15;
//    cols 0-7 = u, 8-15 = z; shfl_xor(8) pairs u/z; 2 accumulator regs;
//    final shfl_xor(16/32) butterfly. No UZ buffer.
//  - live set ~60 VGPR: safely under hipcc's 84-cap for this family.

#define QDIM 128
#define C8 8

typedef __attribute__((ext_vector_type(8))) short s8v;
typedef __attribute__((ext_vector_type(4))) float f4v;

__device__ __forceinline__ unsigned short bf16_rne(float f) {
    union { float f; unsigned u; } v; v.f = f;
    unsigned b = v.u;
    b += 0x7FFFu + ((b >> 16) & 1u);
    return (unsigned short)(b >> 16);
}
__device__ __forceinline__ float bf16f(unsigned short h) {
    union { unsigned u; float f; } v; v.u = ((unsigned)h) << 16;
    return v.f;
}

// bs[j] = first k with seg[k] >= j, j in [0,N]; bs[N] = I.
__global__ void mixmil_bounds(const int* __restrict__ seg, int I, int N,
                              int* __restrict__ bs)
{
    int k = blockIdx.x * blockDim.x + threadIdx.x;
    if (k > I) return;
    int a    = (k < I) ? seg[k]     : N;
    int prev = (k > 0) ? seg[k - 1] : -1;
    for (int j = prev + 1; j <= a; ++j) bs[j] = k;
}

__global__ __launch_bounds__(256) void mixmil_fused(
    const float* __restrict__ x,
    const float* __restrict__ bu,
    const float* __restrict__ bz,
    const int*   __restrict__ bs,
    int I, int N,
    float* __restrict__ xmil)   // [N,8]
{
    // 4 waves x 2 buffers x 8KB = 64KB
    __shared__ float XT[4 * 2 * 2048];

    const int t    = threadIdx.x;
    const int lane = t & 63;
    const int wv   = t >> 6;

    const int mybag = blockIdx.x * 4 + wv;
    if (mybag >= N) return;
    const int lo = bs[mybag];
    const int hi = bs[mybag + 1];

    // B fragments (weights), hi/lo bf16 split. B[k][n]: n=lane&15, k=(lane>>4)*8+j.
    const int bn  = lane & 15;
    const int bkg = lane >> 4;
    s8v BH[4], BL[4];
    const float* wcol = (bn < 8) ? (bu + bn) : (bz + (bn - 8));
#pragma unroll
    for (int kc = 0; kc < 4; ++kc) {
#pragma unroll
        for (int j = 0; j < 8; ++j) {
            const int k = kc * 32 + bkg * 8 + j;
            const float w = wcol[(size_t)k * 8];
            const unsigned short h = bf16_rne(w);
            BH[kc][j] = (short)h;
            BL[kc][j] = (short)bf16_rne(w - bf16f(h));
        }
    }

    float* const myXT = &XT[wv * 4096];       // my wave's 2 buffers
    const int rl   = lane >> 5;               // row offset within 2-row group
    const int c4l  = lane & 31;               // linear float4 col in LDS

    const int nt = (hi - lo + 15) >> 4;       // 16-row tiles in my bag

    // stage(tile j -> buffer sel): 8 x global_load_lds(16B), source pre-swizzled
#define STAGE(J, SEL)                                                          \
    {                                                                          \
        const int base_ = lo + (J) * 16;                                       \
        _Pragma("unroll")                                                      \
        for (int i = 0; i < 8; ++i) {                                          \
            const int r_ = i * 2 + rl;                                         \
            int grow_ = base_ + r_;                                            \
            if (grow_ >= hi) grow_ = hi - 1;                                   \
            const int c4g_ = c4l ^ (r_ & 7);                                   \
            const float* src_ = x + (size_t)grow_ * QDIM + 4 * (size_t)c4g_;   \
            __builtin_amdgcn_global_load_lds(                                  \
                (const __attribute__((address_space(1))) unsigned int*)src_,   \
                (__attribute__((address_space(3))) unsigned int*)              \
                    &myXT[(SEL) * 2048 + i * 256],                             \
                16, 0, 0);                                                     \
        }                                                                      \
    }

    float lsum = 0.f, asum = 0.f;   // this lane's col partials (cols 0-7 only)

    const int am  = lane & 15;      // my A/C row within tile
    const int akg = lane >> 4;
    const int sw  = am & 7;

    if (nt > 0) STAGE(0, 0);

    for (int j = 0; j < nt; ++j) {
        const int sel = j & 1;
        if (j + 1 < nt) {
            STAGE(j + 1, sel ^ 1);
            asm volatile("s_waitcnt vmcnt(8)" ::: "memory");
        } else {
            asm volatile("s_waitcnt vmcnt(0)" ::: "memory");
        }
        __builtin_amdgcn_sched_barrier(0);

        const float* buf = &myXT[sel * 2048];

        f4v acc = {0.f, 0.f, 0.f, 0.f};
#pragma unroll
        for (int kc = 0; kc < 4; ++kc) {
            const int c4a = kc * 8 + akg * 2;
            const float4 xa = *(const float4*)&buf[am * QDIM + 4 * ((c4a    ) ^ sw)];
            const float4 xb = *(const float4*)&buf[am * QDIM + 4 * ((c4a + 1) ^ sw)];
            const float xs[8] = {xa.x, xa.y, xa.z, xa.w, xb.x, xb.y, xb.z, xb.w};
            s8v AH, AL;
#pragma unroll
            for (int jj = 0; jj < 8; ++jj) {
                const unsigned short h = bf16_rne(xs[jj]);
                AH[jj] = (short)h;
                AL[jj] = (short)bf16_rne(xs[jj] - bf16f(h));
            }
            acc = __builtin_amdgcn_mfma_f32_16x16x32_bf16(AH, BH[kc], acc, 0, 0, 0);
            acc = __builtin_amdgcn_mfma_f32_16x16x32_bf16(AH, BL[kc], acc, 0, 0, 0);
            acc = __builtin_amdgcn_mfma_f32_16x16x32_bf16(AL, BH[kc], acc, 0, 0, 0);
        }

        // pool in-register: lane holds C rows (lane>>4)*4+i, col lane&15.
        const int base = lo + j * 16;
        const int r0   = (lane >> 4) * 4;
#pragma unroll
        for (int i = 0; i < 4; ++i) {
            const float uv = acc[i];
            const float zv = __shfl_xor(uv, 8);       // col<8 lanes receive z
            const bool valid = (base + r0 + i) < hi;
            if ((lane & 15) < 8 && valid) {
                const float e = __expf(uv);
                lsum += e;
                asum = fmaf(e, zv, asum);
            }
        }
    }

    // sum the 4 row-groups (lanes c, c+16, c+32, c+48 share col c)
    lsum += __shfl_xor(lsum, 16);
    asum += __shfl_xor(asum, 16);
    lsum += __shfl_xor(lsum, 32);
    asum += __shfl_xor(asum, 32);

    if (lane < 8)
        xmil[(size_t)mybag * 8 + lane] = (hi > lo) ? (asum / lsum) : 0.f;
#undef STAGE
}

// stats + output: per-block redundant stats over xmil (128 KB, L2/L3-hot).
__global__ __launch_bounds__(256) void mixmil_statsout(
    const float* __restrict__ xmil,
    const float* __restrict__ bz,
    int N, int total,
    float* __restrict__ out)
{
    double s[8], qq[8];
    float t2[8];
#pragma unroll
    for (int c = 0; c < 8; ++c) { s[c] = 0.0; qq[c] = 0.0; t2[c] = 0.f; }

    for (int r = threadIdx.x; r < N; r += 256) {
        const float* row = xmil + (size_t)r * 8;
#pragma unroll
        for (int c = 0; c < 8; ++c) {
            float v = row[c];
            s[c] += v;
            qq[c] += (double)v * (double)v;
        }
    }
    for (int r = threadIdx.x; r < QDIM; r += 256) {
        const float* row = bz + (size_t)r * 8;
#pragma unroll
        for (int c = 0; c < 8; ++c) { float v = row[c]; t2[c] = fmaf(v, v, t2[c]); }
    }

    for (int off = 32; off; off >>= 1) {
#pragma unroll
        for (int c = 0; c < 8; ++c) {
            s[c]  += __shfl_xor(s[c], off);
            qq[c] += __shfl_xor(qq[c], off);
            t2[c] += __shfl_xor(t2[c], off);
        }
    }

    __shared__ double S[4][8], QQ[4][8];
    __shared__ float T2[4][8];
    __shared__ float fb[8], fm[8], fr[8];
    const int w = threadIdx.x >> 6;
    if ((threadIdx.x & 63) == 0) {
#pragma unroll
        for (int c = 0; c < 8; ++c) { S[w][c] = s[c]; QQ[w][c] = qq[c]; T2[w][c] = t2[c]; }
    }
    __syncthreads();
    if (threadIdx.x < 8) {
        const int c = threadIdx.x;
        double ss = S[0][c] + S[1][c] + S[2][c] + S[3][c];
        double qs = QQ[0][c] + QQ[1][c] + QQ[2][c] + QQ[3][c];
        float  tt = T2[0][c] + T2[1][c] + T2[2][c] + T2[3][c];
        double mean = ss / (double)N;
        double var  = (qs - ss * ss / (double)N) / (double)(N - 1);
        fb[c] = sqrtf(tt / (float)QDIM);
        fm[c] = (float)mean;
        fr[c] = (float)(1.0 / sqrt(var));
    }
    __syncthreads();

    const int e = blockIdx.x * 256 + threadIdx.x;
    if (e < total) {
        const int c = e & 7;
        out[e] = fb[c] * (xmil[e] - fm[c]) * fr[c];
    }
}

extern "C" void kernel_launch(void* const* d_in, const int* in_sizes, int n_in,
                              void* d_out, int out_size, void* d_ws, size_t ws_size,
                              hipStream_t stream) {
    const float* x  = (const float*)d_in[0];
    const float* bu = (const float*)d_in[1];
    const float* bz = (const float*)d_in[2];
    const int*   sg = (const int*)d_in[3];   // sorted bag ids (int32)

    const int I = in_sizes[0] / QDIM;        // 512000
    const int N = out_size / C8;             // 4000 bags

    // ws layout: xmil[N*8] | bs[N+1]
    float* xmil = (float*)d_ws;
    int*   bs   = (int*)(xmil + (size_t)N * C8);

    mixmil_bounds<<<(I + 256) / 256, 256, 0, stream>>>(sg, I, N, bs);

    mixmil_fused<<<(N + 3) / 4, 256, 0, stream>>>(x, bu, bz, bs, I, N, xmil);

    const int total = N * C8;
    mixmil_statsout<<<(total + 255) / 256, 256, 0, stream>>>(
        xmil, bz, N, total, (float*)d_out);
}

// Round 17
// 63.348 us; speedup vs baseline: 1.0481x; 1.0481x over previous
//
#include <hip/hip_runtime.h>
#include <hip/hip_bf16.h>

// MixMIL — R17: R16 barrier-free fused kernel + HARDWARE bf16 conversions.
// Shapes: I=512000, Q=128, P=1, S=8, N=4000. x f32, betas f32, seg int32 sorted.
//
// Algebra: accumulate with raw beta_z; b = rms(beta_z) applied only at the end.
// Max-free softmax (|u|max ~62 << 88, f32-exp safe; R15/R16-verified).
// 3-MFMA hi/lo bf16 split (R14-verified, absmax 1.56e-2).
//
// R17 change vs R16 (R15==R16 at ~66us -> barriers weren't the limiter; the
// ~10us VALU residual is the hand-rolled bf16_rne bit-twiddle, ~12 ops/float):
//  - hi/lo split now uses __hip_bfloat16 casts -> compiler emits hardware
//    v_cvt_pk_bf16_f32 (~3 ops/float incl. residual). Guide T12/m240: never
//    hand-write conversions the compiler can lower.
// Everything else identical to R16: one bag/wave, per-wave 2x8KB LDS dbuf,
// global_load_lds(16B) with pre-swizzled source cols, counted vmcnt(8),
// zero __syncthreads, in-register pooling via shfl_xor(8/16/32).

#define QDIM 128
#define C8 8

typedef __attribute__((ext_vector_type(8))) short s8v;
typedef __attribute__((ext_vector_type(4))) float f4v;

// hi/lo bf16 split via hardware conversions
__device__ __forceinline__ void split8(const float xs[8], s8v& AH, s8v& AL) {
#pragma unroll
    for (int j = 0; j < 8; ++j) {
        const float xv = xs[j];
        const __hip_bfloat16 hb = __float2bfloat16(xv);       // hw cvt (RNE)
        const float hf = __bfloat162float(hb);                // shift
        const __hip_bfloat16 lb = __float2bfloat16(xv - hf);  // exact residual cvt
        unsigned short hr, lr;
        __builtin_memcpy(&hr, &hb, 2);
        __builtin_memcpy(&lr, &lb, 2);
        AH[j] = (short)hr;
        AL[j] = (short)lr;
    }
}

// bs[j] = first k with seg[k] >= j, j in [0,N]; bs[N] = I.
__global__ void mixmil_bounds(const int* __restrict__ seg, int I, int N,
                              int* __restrict__ bs)
{
    int k = blockIdx.x * blockDim.x + threadIdx.x;
    if (k > I) return;
    int a    = (k < I) ? seg[k]     : N;
    int prev = (k > 0) ? seg[k - 1] : -1;
    for (int j = prev + 1; j <= a; ++j) bs[j] = k;
}

__global__ __launch_bounds__(256) void mixmil_fused(
    const float* __restrict__ x,
    const float* __restrict__ bu,
    const float* __restrict__ bz,
    const int*   __restrict__ bs,
    int I, int N,
    float* __restrict__ xmil)   // [N,8]
{
    // 4 waves x 2 buffers x 8KB = 64KB
    __shared__ float XT[4 * 2 * 2048];

    const int t    = threadIdx.x;
    const int lane = t & 63;
    const int wv   = t >> 6;

    const int mybag = blockIdx.x * 4 + wv;
    if (mybag >= N) return;
    const int lo = bs[mybag];
    const int hi = bs[mybag + 1];

    // B fragments (weights), hi/lo split via hw cvt. B[k][n]: n=lane&15, k=(lane>>4)*8+j.
    const int bn  = lane & 15;
    const int bkg = lane >> 4;
    s8v BH[4], BL[4];
    const float* wcol = (bn < 8) ? (bu + bn) : (bz + (bn - 8));
#pragma unroll
    for (int kc = 0; kc < 4; ++kc) {
        float ws[8];
#pragma unroll
        for (int j = 0; j < 8; ++j)
            ws[j] = wcol[(size_t)(kc * 32 + bkg * 8 + j) * 8];
        split8(ws, BH[kc], BL[kc]);
    }

    float* const myXT = &XT[wv * 4096];       // my wave's 2 buffers
    const int rl   = lane >> 5;               // row offset within 2-row group
    const int c4l  = lane & 31;               // linear float4 col in LDS

    const int nt = (hi - lo + 15) >> 4;       // 16-row tiles in my bag

#define STAGE(J, SEL)                                                          \
    {                                                                          \
        const int base_ = lo + (J) * 16;                                       \
        _Pragma("unroll")                                                      \
        for (int i = 0; i < 8; ++i) {                                          \
            const int r_ = i * 2 + rl;                                         \
            int grow_ = base_ + r_;                                            \
            if (grow_ >= hi) grow_ = hi - 1;                                   \
            const int c4g_ = c4l ^ (r_ & 7);                                   \
            const float* src_ = x + (size_t)grow_ * QDIM + 4 * (size_t)c4g_;   \
            __builtin_amdgcn_global_load_lds(                                  \
                (const __attribute__((address_space(1))) unsigned int*)src_,   \
                (__attribute__((address_space(3))) unsigned int*)              \
                    &myXT[(SEL) * 2048 + i * 256],                             \
                16, 0, 0);                                                     \
        }                                                                      \
    }

    float lsum = 0.f, asum = 0.f;   // this lane's col partials (cols 0-7 only)

    const int am  = lane & 15;      // my A/C row within tile
    const int akg = lane >> 4;
    const int sw  = am & 7;

    if (nt > 0) STAGE(0, 0);

    for (int j = 0; j < nt; ++j) {
        const int sel = j & 1;
        if (j + 1 < nt) {
            STAGE(j + 1, sel ^ 1);
            asm volatile("s_waitcnt vmcnt(8)" ::: "memory");
        } else {
            asm volatile("s_waitcnt vmcnt(0)" ::: "memory");
        }
        __builtin_amdgcn_sched_barrier(0);

        const float* buf = &myXT[sel * 2048];

        f4v acc = {0.f, 0.f, 0.f, 0.f};
#pragma unroll
        for (int kc = 0; kc < 4; ++kc) {
            const int c4a = kc * 8 + akg * 2;
            const float4 xa = *(const float4*)&buf[am * QDIM + 4 * ((c4a    ) ^ sw)];
            const float4 xb = *(const float4*)&buf[am * QDIM + 4 * ((c4a + 1) ^ sw)];
            const float xs[8] = {xa.x, xa.y, xa.z, xa.w, xb.x, xb.y, xb.z, xb.w};
            s8v AH, AL;
            split8(xs, AH, AL);
            acc = __builtin_amdgcn_mfma_f32_16x16x32_bf16(AH, BH[kc], acc, 0, 0, 0);
            acc = __builtin_amdgcn_mfma_f32_16x16x32_bf16(AH, BL[kc], acc, 0, 0, 0);
            acc = __builtin_amdgcn_mfma_f32_16x16x32_bf16(AL, BH[kc], acc, 0, 0, 0);
        }

        // pool in-register: lane holds C rows (lane>>4)*4+i, col lane&15.
        const int base = lo + j * 16;
        const int r0   = (lane >> 4) * 4;
#pragma unroll
        for (int i = 0; i < 4; ++i) {
            const float uv = acc[i];
            const float zv = __shfl_xor(uv, 8);       // col<8 lanes receive z
            const bool valid = (base + r0 + i) < hi;
            if ((lane & 15) < 8 && valid) {
                const float e = __expf(uv);
                lsum += e;
                asum = fmaf(e, zv, asum);
            }
        }
    }

    // sum the 4 row-groups (lanes c, c+16, c+32, c+48 share col c)
    lsum += __shfl_xor(lsum, 16);
    asum += __shfl_xor(asum, 16);
    lsum += __shfl_xor(lsum, 32);
    asum += __shfl_xor(asum, 32);

    if (lane < 8)
        xmil[(size_t)mybag * 8 + lane] = (hi > lo) ? (asum / lsum) : 0.f;
#undef STAGE
}

// stats + output: per-block redundant stats over xmil (128 KB, L2/L3-hot).
__global__ __launch_bounds__(256) void mixmil_statsout(
    const float* __restrict__ xmil,
    const float* __restrict__ bz,
    int N, int total,
    float* __restrict__ out)
{
    double s[8], qq[8];
    float t2[8];
#pragma unroll
    for (int c = 0; c < 8; ++c) { s[c] = 0.0; qq[c] = 0.0; t2[c] = 0.f; }

    for (int r = threadIdx.x; r < N; r += 256) {
        const float* row = xmil + (size_t)r * 8;
#pragma unroll
        for (int c = 0; c < 8; ++c) {
            float v = row[c];
            s[c] += v;
            qq[c] += (double)v * (double)v;
        }
    }
    for (int r = threadIdx.x; r < QDIM; r += 256) {
        const float* row = bz + (size_t)r * 8;
#pragma unroll
        for (int c = 0; c < 8; ++c) { float v = row[c]; t2[c] = fmaf(v, v, t2[c]); }
    }

    for (int off = 32; off; off >>= 1) {
#pragma unroll
        for (int c = 0; c < 8; ++c) {
            s[c]  += __shfl_xor(s[c], off);
            qq[c] += __shfl_xor(qq[c], off);
            t2[c] += __shfl_xor(t2[c], off);
        }
    }

    __shared__ double S[4][8], QQ[4][8];
    __shared__ float T2[4][8];
    __shared__ float fb[8], fm[8], fr[8];
    const int w = threadIdx.x >> 6;
    if ((threadIdx.x & 63) == 0) {
#pragma unroll
        for (int c = 0; c < 8; ++c) { S[w][c] = s[c]; QQ[w][c] = qq[c]; T2[w][c] = t2[c]; }
    }
    __syncthreads();
    if (threadIdx.x < 8) {
        const int c = threadIdx.x;
        double ss = S[0][c] + S[1][c] + S[2][c] + S[3][c];
        double qs = QQ[0][c] + QQ[1][c] + QQ[2][c] + QQ[3][c];
        float  tt = T2[0][c] + T2[1][c] + T2[2][c] + T2[3][c];
        double mean = ss / (double)N;
        double var  = (qs - ss * ss / (double)N) / (double)(N - 1);
        fb[c] = sqrtf(tt / (float)QDIM);
        fm[c] = (float)mean;
        fr[c] = (float)(1.0 / sqrt(var));
    }
    __syncthreads();

    const int e = blockIdx.x * 256 + threadIdx.x;
    if (e < total) {
        const int c = e & 7;
        out[e] = fb[c] * (xmil[e] - fm[c]) * fr[c];
    }
}

extern "C" void kernel_launch(void* const* d_in, const int* in_sizes, int n_in,
                              void* d_out, int out_size, void* d_ws, size_t ws_size,
                              hipStream_t stream) {
    const float* x  = (const float*)d_in[0];
    const float* bu = (const float*)d_in[1];
    const float* bz = (const float*)d_in[2];
    const int*   sg = (const int*)d_in[3];   // sorted bag ids (int32)

    const int I = in_sizes[0] / QDIM;        // 512000
    const int N = out_size / C8;             // 4000 bags

    // ws layout: xmil[N*8] | bs[N+1]
    float* xmil = (float*)d_ws;
    int*   bs   = (int*)(xmil + (size_t)N * C8);

    mixmil_bounds<<<(I + 256) / 256, 256, 0, stream>>>(sg, I, N, bs);

    mixmil_fused<<<(N + 3) / 4, 256, 0, stream>>>(x, bu, bz, bs, I, N, xmil);

    const int total = N * C8;
    mixmil_statsout<<<(total + 255) / 256, 256, 0, stream>>>(
        xmil, bz, N, total, (float*)d_out);
}

// Round 18
// 62.622 us; speedup vs baseline: 1.0603x; 1.0116x over previous
//
#include <hip/hip_runtime.h>
#include <hip/hip_bf16.h>

// MixMIL — R18: persistent-wave fused kernel; staging pipeline never drains
// across bag boundaries.
// Shapes: I=512000, Q=128, P=1, S=8, N=4000. x f32, betas f32, seg int32 sorted.
//
// Algebra: accumulate with raw beta_z; b = rms(beta_z) applied only at the end.
// Max-free softmax (|u|max ~62 << 88; R15-R17-verified).
// 3-MFMA hi/lo bf16 split, hardware cvts (R17, absmax 1.56e-2).
//
// R18 change vs R17 (fused ~52us vs 42us floor; per-bag vmcnt(0) drains +
// block-round-2 cold start ~6-8us/CU of dead memory time):
//  - grid = ceil(N/8) = 500 blocks, ALL co-resident (2 blocks/CU x 256 = 512):
//    single occupancy round.
//  - each wave owns 2 bags (b, b+2000); bounds preloaded at wave start (no
//    mid-loop bs loads -> vmcnt discipline intact); tiles of both bags
//    flattened into one chunk stream; double-buffer staging runs continuously
//    across the bag boundary; vmcnt(0) only once per WAVE.
//  - finalize (shfl butterfly + write + reset) happens between computes while
//    the next bag's tile is already in flight.
//  - exactly-8-loads-per-chunk invariant kept (clamped tail rows; duplicates
//    hit the same line -> L2-absorbed, near-zero HBM waste).

#define QDIM 128
#define C8 8

typedef __attribute__((ext_vector_type(8))) short s8v;
typedef __attribute__((ext_vector_type(4))) float f4v;

// hi/lo bf16 split via hardware conversions
__device__ __forceinline__ void split8(const float xs[8], s8v& AH, s8v& AL) {
#pragma unroll
    for (int j = 0; j < 8; ++j) {
        const float xv = xs[j];
        const __hip_bfloat16 hb = __float2bfloat16(xv);       // hw cvt (RNE)
        const float hf = __bfloat162float(hb);                // shift
        const __hip_bfloat16 lb = __float2bfloat16(xv - hf);  // exact residual cvt
        unsigned short hr, lr;
        __builtin_memcpy(&hr, &hb, 2);
        __builtin_memcpy(&lr, &lb, 2);
        AH[j] = (short)hr;
        AL[j] = (short)lr;
    }
}

// bs[j] = first k with seg[k] >= j, j in [0,N]; bs[N] = I.
__global__ void mixmil_bounds(const int* __restrict__ seg, int I, int N,
                              int* __restrict__ bs)
{
    int k = blockIdx.x * blockDim.x + threadIdx.x;
    if (k > I) return;
    int a    = (k < I) ? seg[k]     : N;
    int prev = (k > 0) ? seg[k - 1] : -1;
    for (int j = prev + 1; j <= a; ++j) bs[j] = k;
}

__global__ __launch_bounds__(256) void mixmil_fused(
    const float* __restrict__ x,
    const float* __restrict__ bu,
    const float* __restrict__ bz,
    const int*   __restrict__ bs,
    int I, int N, int bstride,   // bstride = 4*gridDim = bag stride between a wave's bags
    float* __restrict__ xmil)    // [N,8]
{
    // 4 waves x 2 buffers x 8KB = 64KB
    __shared__ float XT[4 * 2 * 2048];

    const int t    = threadIdx.x;
    const int lane = t & 63;
    const int wv   = t >> 6;

    const int b0 = blockIdx.x * 4 + wv;          // first bag
    const int b1 = b0 + bstride;                 // second bag (may be >= N)
    if (b0 >= N) return;

    // Preload both bags' bounds now: no vector-mem loads later in the loop.
    const int lo0 = bs[b0], hi0 = bs[b0 + 1];
    int lo1 = 0, hi1 = 0;
    if (b1 < N) { lo1 = bs[b1]; hi1 = bs[b1 + 1]; }
    const int nt0 = (hi0 - lo0 + 15) >> 4;
    const int nt1 = (hi1 - lo1 + 15) >> 4;
    const int total = nt0 + nt1;

    // Empty-bag zero writes (finalize below only runs for bags with >=1 tile).
    if (lane < 8) {
        if (nt0 == 0) xmil[(size_t)b0 * 8 + lane] = 0.f;
        if (b1 < N && nt1 == 0) xmil[(size_t)b1 * 8 + lane] = 0.f;
    }
    if (total == 0) return;

    // B fragments (weights), hi/lo split via hw cvt. B[k][n]: n=lane&15, k=(lane>>4)*8+j.
    const int bn  = lane & 15;
    const int bkg = lane >> 4;
    s8v BH[4], BL[4];
    const float* wcol = (bn < 8) ? (bu + bn) : (bz + (bn - 8));
#pragma unroll
    for (int kc = 0; kc < 4; ++kc) {
        float ws[8];
#pragma unroll
        for (int j = 0; j < 8; ++j)
            ws[j] = wcol[(size_t)(kc * 32 + bkg * 8 + j) * 8];
        split8(ws, BH[kc], BL[kc]);
    }

    float* const myXT = &XT[wv * 4096];       // my wave's 2 buffers
    const int rl  = lane >> 5;                // row offset within 2-row group
    const int c4l = lane & 31;                // linear float4 col in LDS

    // chunk c params: bag0 tiles [0,nt0), bag1 tiles [nt0,total)
#define CH_BASE(C) (((C) >= nt0) ? (lo1 + (((C) - nt0) << 4)) : (lo0 + ((C) << 4)))
#define CH_LIM(C)  (((C) >= nt0) ? hi1 : hi0)

    // stage chunk C into buffer (C)&1 — always exactly 8 load instructions
#define STAGE(C)                                                               \
    {                                                                          \
        const int base_ = CH_BASE(C);                                          \
        const int lim_  = CH_LIM(C);                                           \
        float* dst_ = &myXT[((C) & 1) * 2048];                                 \
        _Pragma("unroll")                                                      \
        for (int i = 0; i < 8; ++i) {                                          \
            const int r_ = i * 2 + rl;                                         \
            int grow_ = base_ + r_;                                            \
            if (grow_ >= lim_) grow_ = lim_ - 1;                               \
            const int c4g_ = c4l ^ (r_ & 7);                                   \
            const float* src_ = x + (size_t)grow_ * QDIM + 4 * (size_t)c4g_;   \
            __builtin_amdgcn_global_load_lds(                                  \
                (const __attribute__((address_space(1))) unsigned int*)src_,   \
                (__attribute__((address_space(3))) unsigned int*)              \
                    (dst_ + i * 256),                                          \
                16, 0, 0);                                                     \
        }                                                                      \
    }

    float lsum = 0.f, asum = 0.f;   // this lane's col partials (cols 0-7 only)

    const int am  = lane & 15;      // my A/C row within tile
    const int akg = lane >> 4;
    const int sw  = am & 7;

    STAGE(0);

    for (int c = 0; c < total; ++c) {
        if (c + 1 < total) {
            STAGE(c + 1);
            asm volatile("s_waitcnt vmcnt(8)" ::: "memory");
        } else {
            asm volatile("s_waitcnt vmcnt(0)" ::: "memory");
        }
        __builtin_amdgcn_sched_barrier(0);

        const float* buf = &myXT[(c & 1) * 2048];

        f4v acc = {0.f, 0.f, 0.f, 0.f};
#pragma unroll
        for (int kc = 0; kc < 4; ++kc) {
            const int c4a = kc * 8 + akg * 2;
            const float4 xa = *(const float4*)&buf[am * QDIM + 4 * ((c4a    ) ^ sw)];
            const float4 xb = *(const float4*)&buf[am * QDIM + 4 * ((c4a + 1) ^ sw)];
            const float xs[8] = {xa.x, xa.y, xa.z, xa.w, xb.x, xb.y, xb.z, xb.w};
            s8v AH, AL;
            split8(xs, AH, AL);
            acc = __builtin_amdgcn_mfma_f32_16x16x32_bf16(AH, BH[kc], acc, 0, 0, 0);
            acc = __builtin_amdgcn_mfma_f32_16x16x32_bf16(AH, BL[kc], acc, 0, 0, 0);
            acc = __builtin_amdgcn_mfma_f32_16x16x32_bf16(AL, BH[kc], acc, 0, 0, 0);
        }

        // pool in-register: lane holds C rows (lane>>4)*4+i, col lane&15.
        const int base = CH_BASE(c);
        const int lim  = CH_LIM(c);
        const int r0   = (lane >> 4) * 4;
#pragma unroll
        for (int i = 0; i < 4; ++i) {
            const float uv = acc[i];
            const float zv = __shfl_xor(uv, 8);       // col<8 lanes receive z
            const bool valid = (base + r0 + i) < lim;
            if ((lane & 15) < 8 && valid) {
                const float e = __expf(uv);
                lsum += e;
                asum = fmaf(e, zv, asum);
            }
        }

        // finalize a bag when its last tile was just pooled
        const bool fin0 = (c == nt0 - 1);
        const bool fin1 = (c == total - 1) && (nt1 > 0);
        if (fin0 || fin1) {
            float ls = lsum, as = asum;
            ls += __shfl_xor(ls, 16);
            as += __shfl_xor(as, 16);
            ls += __shfl_xor(ls, 32);
            as += __shfl_xor(as, 32);
            const int bag = fin0 ? b0 : b1;
            if (lane < 8)
                xmil[(size_t)bag * 8 + lane] = as / ls;
            lsum = 0.f; asum = 0.f;
        }
    }
#undef STAGE
#undef CH_BASE
#undef CH_LIM
}

// stats + output: per-block redundant stats over xmil (128 KB, L2/L3-hot).
__global__ __launch_bounds__(256) void mixmil_statsout(
    const float* __restrict__ xmil,
    const float* __restrict__ bz,
    int N, int total,
    float* __restrict__ out)
{
    double s[8], qq[8];
    float t2[8];
#pragma unroll
    for (int c = 0; c < 8; ++c) { s[c] = 0.0; qq[c] = 0.0; t2[c] = 0.f; }

    for (int r = threadIdx.x; r < N; r += 256) {
        const float* row = xmil + (size_t)r * 8;
#pragma unroll
        for (int c = 0; c < 8; ++c) {
            float v = row[c];
            s[c] += v;
            qq[c] += (double)v * (double)v;
        }
    }
    for (int r = threadIdx.x; r < QDIM; r += 256) {
        const float* row = bz + (size_t)r * 8;
#pragma unroll
        for (int c = 0; c < 8; ++c) { float v = row[c]; t2[c] = fmaf(v, v, t2[c]); }
    }

    for (int off = 32; off; off >>= 1) {
#pragma unroll
        for (int c = 0; c < 8; ++c) {
            s[c]  += __shfl_xor(s[c], off);
            qq[c] += __shfl_xor(qq[c], off);
            t2[c] += __shfl_xor(t2[c], off);
        }
    }

    __shared__ double S[4][8], QQ[4][8];
    __shared__ float T2[4][8];
    __shared__ float fb[8], fm[8], fr[8];
    const int w = threadIdx.x >> 6;
    if ((threadIdx.x & 63) == 0) {
#pragma unroll
        for (int c = 0; c < 8; ++c) { S[w][c] = s[c]; QQ[w][c] = qq[c]; T2[w][c] = t2[c]; }
    }
    __syncthreads();
    if (threadIdx.x < 8) {
        const int c = threadIdx.x;
        double ss = S[0][c] + S[1][c] + S[2][c] + S[3][c];
        double qs = QQ[0][c] + QQ[1][c] + QQ[2][c] + QQ[3][c];
        float  tt = T2[0][c] + T2[1][c] + T2[2][c] + T2[3][c];
        double mean = ss / (double)N;
        double var  = (qs - ss * ss / (double)N) / (double)(N - 1);
        fb[c] = sqrtf(tt / (float)QDIM);
        fm[c] = (float)mean;
        fr[c] = (float)(1.0 / sqrt(var));
    }
    __syncthreads();

    const int e = blockIdx.x * 256 + threadIdx.x;
    if (e < total) {
        const int c = e & 7;
        out[e] = fb[c] * (xmil[e] - fm[c]) * fr[c];
    }
}

extern "C" void kernel_launch(void* const* d_in, const int* in_sizes, int n_in,
                              void* d_out, int out_size, void* d_ws, size_t ws_size,
                              hipStream_t stream) {
    const float* x  = (const float*)d_in[0];
    const float* bu = (const float*)d_in[1];
    const float* bz = (const float*)d_in[2];
    const int*   sg = (const int*)d_in[3];   // sorted bag ids (int32)

    const int I = in_sizes[0] / QDIM;        // 512000
    const int N = out_size / C8;             // 4000 bags

    // grid: 2 bags per wave -> ceil(N/8) blocks; all co-resident (<=512).
    const int nblk = (N + 7) / 8;            // 500
    const int bstride = nblk * 4;            // 2000

    // ws layout: xmil[N*8] | bs[N+1]
    float* xmil = (float*)d_ws;
    int*   bs   = (int*)(xmil + (size_t)N * C8);

    mixmil_bounds<<<(I + 256) / 256, 256, 0, stream>>>(sg, I, N, bs);

    mixmil_fused<<<nblk, 256, 0, stream>>>(x, bu, bz, bs, I, N, bstride, xmil);

    const int total = N * C8;
    mixmil_statsout<<<(total + 255) / 256, 256, 0, stream>>>(
        xmil, bz, N, total, (float*)d_out);
}

// Round 19
// 60.982 us; speedup vs baseline: 1.0888x; 1.0269x over previous
//
#include <hip/hip_runtime.h>
#include <hip/hip_bf16.h>

// MixMIL — R19: R18 persistent-wave fused kernel + in-wave binary-search
// bounds (bounds kernel deleted; 2 kernels total).
// Shapes: I=512000, Q=128, P=1, S=8, N=4000. x f32, betas f32, seg int32 sorted.
//
// Algebra: accumulate with raw beta_z; b = rms(beta_z) applied only at the end.
// Max-free softmax (|u|max ~62 << 88; R15-R18-verified).
// 3-MFMA hi/lo bf16 split, hardware cvts (R17, absmax 1.56e-2).
//
// R19 change vs R18 (62.6us; R16/R18 schedule nulls => fused loop is at the
// HBM service rate ~5.2 TB/s; remaining removable cost is launch structure):
//  - bounds kernel + launch gap (~4-5us) deleted. Each wave needs only
//    bs[b0], bs[b0+1], bs[b1], bs[b1+1]: lanes 0-3 binary-search seg in
//    PARALLEL (19 dependent L2 loads, one pass), broadcast via __shfl.
//  - everything else identical to R18: one bag per wave x 2 bags, per-wave
//    2x8KB LDS dbuf, global_load_lds(16B) pre-swizzled source, counted
//    vmcnt(8), zero __syncthreads, in-register pooling, single vmcnt(0)/wave.

#define QDIM 128
#define C8 8

typedef __attribute__((ext_vector_type(8))) short s8v;
typedef __attribute__((ext_vector_type(4))) float f4v;

// hi/lo bf16 split via hardware conversions
__device__ __forceinline__ void split8(const float xs[8], s8v& AH, s8v& AL) {
#pragma unroll
    for (int j = 0; j < 8; ++j) {
        const float xv = xs[j];
        const __hip_bfloat16 hb = __float2bfloat16(xv);       // hw cvt (RNE)
        const float hf = __bfloat162float(hb);                // shift
        const __hip_bfloat16 lb = __float2bfloat16(xv - hf);  // exact residual cvt
        unsigned short hr, lr;
        __builtin_memcpy(&hr, &hb, 2);
        __builtin_memcpy(&lr, &lb, 2);
        AH[j] = (short)hr;
        AL[j] = (short)lr;
    }
}

__global__ __launch_bounds__(256) void mixmil_fused(
    const float* __restrict__ x,
    const float* __restrict__ bu,
    const float* __restrict__ bz,
    const int*   __restrict__ seg,
    int I, int N, int bstride,   // bstride = 4*gridDim
    float* __restrict__ xmil)    // [N,8]
{
    // 4 waves x 2 buffers x 8KB = 64KB
    __shared__ float XT[4 * 2 * 2048];

    const int t    = threadIdx.x;
    const int lane = t & 63;
    const int wv   = t >> 6;

    const int b0 = blockIdx.x * 4 + wv;          // first bag
    const int b1 = b0 + bstride;                 // second bag (may be >= N)
    if (b0 >= N) return;

    // In-wave bounds: lanes 0-3 binary-search seg for j = b0, b0+1, b1, b1+1
    // (lower bound: first k with seg[k] >= j). Other lanes search j=N (cheap).
    int jq = N;
    if (lane == 0) jq = b0;
    else if (lane == 1) jq = b0 + 1;
    else if (lane == 2) jq = (b1 < N) ? b1 : N;
    else if (lane == 3) jq = (b1 + 1 < N) ? (b1 + 1) : N;
    int slo = 0, shi = I;
    while (slo < shi) {
        const int mid = (slo + shi) >> 1;
        if (seg[mid] < jq) slo = mid + 1; else shi = mid;
    }
    const int lo0 = __shfl(slo, 0);
    const int hi0 = __shfl(slo, 1);
    int lo1 = 0, hi1 = 0;
    if (b1 < N) { lo1 = __shfl(slo, 2); hi1 = __shfl(slo, 3); }

    const int nt0 = (hi0 - lo0 + 15) >> 4;
    const int nt1 = (hi1 - lo1 + 15) >> 4;
    const int total = nt0 + nt1;

    // Empty-bag zero writes (finalize below only runs for bags with >=1 tile).
    if (lane < 8) {
        if (nt0 == 0) xmil[(size_t)b0 * 8 + lane] = 0.f;
        if (b1 < N && nt1 == 0) xmil[(size_t)b1 * 8 + lane] = 0.f;
    }
    if (total == 0) return;

    // B fragments (weights), hi/lo split via hw cvt. B[k][n]: n=lane&15, k=(lane>>4)*8+j.
    const int bn  = lane & 15;
    const int bkg = lane >> 4;
    s8v BH[4], BL[4];
    const float* wcol = (bn < 8) ? (bu + bn) : (bz + (bn - 8));
#pragma unroll
    for (int kc = 0; kc < 4; ++kc) {
        float ws[8];
#pragma unroll
        for (int j = 0; j < 8; ++j)
            ws[j] = wcol[(size_t)(kc * 32 + bkg * 8 + j) * 8];
        split8(ws, BH[kc], BL[kc]);
    }

    float* const myXT = &XT[wv * 4096];       // my wave's 2 buffers
    const int rl  = lane >> 5;                // row offset within 2-row group
    const int c4l = lane & 31;                // linear float4 col in LDS

    // chunk c params: bag0 tiles [0,nt0), bag1 tiles [nt0,total)
#define CH_BASE(C) (((C) >= nt0) ? (lo1 + (((C) - nt0) << 4)) : (lo0 + ((C) << 4)))
#define CH_LIM(C)  (((C) >= nt0) ? hi1 : hi0)

    // stage chunk C into buffer (C)&1 — always exactly 8 load instructions
#define STAGE(C)                                                               \
    {                                                                          \
        const int base_ = CH_BASE(C);                                          \
        const int lim_  = CH_LIM(C);                                           \
        float* dst_ = &myXT[((C) & 1) * 2048];                                 \
        _Pragma("unroll")                                                      \
        for (int i = 0; i < 8; ++i) {                                          \
            const int r_ = i * 2 + rl;                                         \
            int grow_ = base_ + r_;                                            \
            if (grow_ >= lim_) grow_ = lim_ - 1;                               \
            const int c4g_ = c4l ^ (r_ & 7);                                   \
            const float* src_ = x + (size_t)grow_ * QDIM + 4 * (size_t)c4g_;   \
            __builtin_amdgcn_global_load_lds(                                  \
                (const __attribute__((address_space(1))) unsigned int*)src_,   \
                (__attribute__((address_space(3))) unsigned int*)              \
                    (dst_ + i * 256),                                          \
                16, 0, 0);                                                     \
        }                                                                      \
    }

    float lsum = 0.f, asum = 0.f;   // this lane's col partials (cols 0-7 only)

    const int am  = lane & 15;      // my A/C row within tile
    const int akg = lane >> 4;
    const int sw  = am & 7;

    STAGE(0);

    for (int c = 0; c < total; ++c) {
        if (c + 1 < total) {
            STAGE(c + 1);
            asm volatile("s_waitcnt vmcnt(8)" ::: "memory");
        } else {
            asm volatile("s_waitcnt vmcnt(0)" ::: "memory");
        }
        __builtin_amdgcn_sched_barrier(0);

        const float* buf = &myXT[(c & 1) * 2048];

        f4v acc = {0.f, 0.f, 0.f, 0.f};
#pragma unroll
        for (int kc = 0; kc < 4; ++kc) {
            const int c4a = kc * 8 + akg * 2;
            const float4 xa = *(const float4*)&buf[am * QDIM + 4 * ((c4a    ) ^ sw)];
            const float4 xb = *(const float4*)&buf[am * QDIM + 4 * ((c4a + 1) ^ sw)];
            const float xs[8] = {xa.x, xa.y, xa.z, xa.w, xb.x, xb.y, xb.z, xb.w};
            s8v AH, AL;
            split8(xs, AH, AL);
            acc = __builtin_amdgcn_mfma_f32_16x16x32_bf16(AH, BH[kc], acc, 0, 0, 0);
            acc = __builtin_amdgcn_mfma_f32_16x16x32_bf16(AH, BL[kc], acc, 0, 0, 0);
            acc = __builtin_amdgcn_mfma_f32_16x16x32_bf16(AL, BH[kc], acc, 0, 0, 0);
        }

        // pool in-register: lane holds C rows (lane>>4)*4+i, col lane&15.
        const int base = CH_BASE(c);
        const int lim  = CH_LIM(c);
        const int r0   = (lane >> 4) * 4;
#pragma unroll
        for (int i = 0; i < 4; ++i) {
            const float uv = acc[i];
            const float zv = __shfl_xor(uv, 8);       // col<8 lanes receive z
            const bool valid = (base + r0 + i) < lim;
            if ((lane & 15) < 8 && valid) {
                const float e = __expf(uv);
                lsum += e;
                asum = fmaf(e, zv, asum);
            }
        }

        // finalize a bag when its last tile was just pooled
        const bool fin0 = (c == nt0 - 1);
        const bool fin1 = (c == total - 1) && (nt1 > 0);
        if (fin0 || fin1) {
            float ls = lsum, as = asum;
            ls += __shfl_xor(ls, 16);
            as += __shfl_xor(as, 16);
            ls += __shfl_xor(ls, 32);
            as += __shfl_xor(as, 32);
            const int bag = fin0 ? b0 : b1;
            if (lane < 8)
                xmil[(size_t)bag * 8 + lane] = as / ls;
            lsum = 0.f; asum = 0.f;
        }
    }
#undef STAGE
#undef CH_BASE
#undef CH_LIM
}

// stats + output: per-block redundant stats over xmil (128 KB, L2/L3-hot).
__global__ __launch_bounds__(256) void mixmil_statsout(
    const float* __restrict__ xmil,
    const float* __restrict__ bz,
    int N, int total,
    float* __restrict__ out)
{
    double s[8], qq[8];
    float t2[8];
#pragma unroll
    for (int c = 0; c < 8; ++c) { s[c] = 0.0; qq[c] = 0.0; t2[c] = 0.f; }

    for (int r = threadIdx.x; r < N; r += 256) {
        const float* row = xmil + (size_t)r * 8;
#pragma unroll
        for (int c = 0; c < 8; ++c) {
            float v = row[c];
            s[c] += v;
            qq[c] += (double)v * (double)v;
        }
    }
    for (int r = threadIdx.x; r < QDIM; r += 256) {
        const float* row = bz + (size_t)r * 8;
#pragma unroll
        for (int c = 0; c < 8; ++c) { float v = row[c]; t2[c] = fmaf(v, v, t2[c]); }
    }

    for (int off = 32; off; off >>= 1) {
#pragma unroll
        for (int c = 0; c < 8; ++c) {
            s[c]  += __shfl_xor(s[c], off);
            qq[c] += __shfl_xor(qq[c], off);
            t2[c] += __shfl_xor(t2[c], off);
        }
    }

    __shared__ double S[4][8], QQ[4][8];
    __shared__ float T2[4][8];
    __shared__ float fb[8], fm[8], fr[8];
    const int w = threadIdx.x >> 6;
    if ((threadIdx.x & 63) == 0) {
#pragma unroll
        for (int c = 0; c < 8; ++c) { S[w][c] = s[c]; QQ[w][c] = qq[c]; T2[w][c] = t2[c]; }
    }
    __syncthreads();
    if (threadIdx.x < 8) {
        const int c = threadIdx.x;
        double ss = S[0][c] + S[1][c] + S[2][c] + S[3][c];
        double qs = QQ[0][c] + QQ[1][c] + QQ[2][c] + QQ[3][c];
        float  tt = T2[0][c] + T2[1][c] + T2[2][c] + T2[3][c];
        double mean = ss / (double)N;
        double var  = (qs - ss * ss / (double)N) / (double)(N - 1);
        fb[c] = sqrtf(tt / (float)QDIM);
        fm[c] = (float)mean;
        fr[c] = (float)(1.0 / sqrt(var));
    }
    __syncthreads();

    const int e = blockIdx.x * 256 + threadIdx.x;
    if (e < total) {
        const int c = e & 7;
        out[e] = fb[c] * (xmil[e] - fm[c]) * fr[c];
    }
}

extern "C" void kernel_launch(void* const* d_in, const int* in_sizes, int n_in,
                              void* d_out, int out_size, void* d_ws, size_t ws_size,
                              hipStream_t stream) {
    const float* x  = (const float*)d_in[0];
    const float* bu = (const float*)d_in[1];
    const float* bz = (const float*)d_in[2];
    const int*   sg = (const int*)d_in[3];   // sorted bag ids (int32)

    const int I = in_sizes[0] / QDIM;        // 512000
    const int N = out_size / C8;             // 4000 bags

    // grid: 2 bags per wave -> ceil(N/8) blocks; all co-resident (<=512).
    const int nblk = (N + 7) / 8;            // 500
    const int bstride = nblk * 4;            // 2000

    // ws layout: xmil[N*8]
    float* xmil = (float*)d_ws;

    mixmil_fused<<<nblk, 256, 0, stream>>>(x, bu, bz, sg, I, N, bstride, xmil);

    const int total = N * C8;
    mixmil_statsout<<<(total + 255) / 256, 256, 0, stream>>>(
        xmil, bz, N, total, (float*)d_out);
}